// Round 20
// baseline (400.196 us; speedup 1.0000x reference)
//
#include <hip/hip_runtime.h>
#include <math.h>

#define BATCH 8
#define NPTS 2048
#define MPTS 2048
#define TPB 256                       // 4 waves
#define RPB 32                       // rows per block
#define KC 8                          // columns per thread: 2048/256
#define RPR 8                         // rows per round (R20: 4 -> 8)
#define NRND (RPB/RPR)                // 4 rounds
#define CHUNKS (NPTS/RPB)             // 64
#define NBLK (BATCH*CHUNKS)           // 512

// Persistent state (re-initialized every kernel_launch -> deterministic).
// colsum rotation: level l reads g_cbuf[l%3], accumulates into g_cbuf[(l+1)%3],
// zeroes g_cbuf[(l+2)%3]. remainr ping-pongs g_rbuf[l&1] -> g_rbuf[(l+1)&1].
// rr/zero global writes gated to chunk==0 (identical values across blocks).
__device__ float  g_remainl[BATCH*NPTS];
__device__ float  g_s[BATCH*NPTS];
__device__ float  g_rbuf[2][BATCH*MPTS];
__device__ float  g_cbuf[3][BATCH*MPTS];
__device__ float4 g_gt4[BATCH*MPTS];   // (x, y, z, |c|^2)
__device__ float4 g_gen4[BATCH*NPTS];  // (-2x, -2y, -2z, |g|^2)
__device__ float  g_cost;

#if __has_builtin(__builtin_amdgcn_exp2f)
#define EXP2(x) __builtin_amdgcn_exp2f(x)
#else
#define EXP2(x) exp2f(x)
#endif
#if __has_builtin(__builtin_amdgcn_sqrtf)
#define FSQRT(x) __builtin_amdgcn_sqrtf(x)
#else
#define FSQRT(x) sqrtf(x)
#endif
#if __has_builtin(__builtin_amdgcn_rcpf)
#define RCP(x) __builtin_amdgcn_rcpf(x)
#else
#define RCP(x) (1.0f/(x))
#endif

template<int CTRL>
__device__ __forceinline__ float dpp_add(float x) {
  const int y = __builtin_amdgcn_update_dpp(0, __float_as_int(x),
                                            CTRL, 0xF, 0xF, true);
  return x + __int_as_float(y);
}
__device__ __forceinline__ void wsum_step4(float& a, float& b, float& c, float& d) {
  a = dpp_add<0xB1>(a);  b = dpp_add<0xB1>(b);
  c = dpp_add<0xB1>(c);  d = dpp_add<0xB1>(d);
  a = dpp_add<0x4E>(a);  b = dpp_add<0x4E>(b);
  c = dpp_add<0x4E>(c);  d = dpp_add<0x4E>(d);
  a = dpp_add<0x141>(a); b = dpp_add<0x141>(b);
  c = dpp_add<0x141>(c); d = dpp_add<0x141>(d);
  a = dpp_add<0x140>(a); b = dpp_add<0x140>(b);
  c = dpp_add<0x140>(c); d = dpp_add<0x140>(d);
  a += __shfl_xor(a, 16); b += __shfl_xor(b, 16);
  c += __shfl_xor(c, 16); d += __shfl_xor(d, 16);
  a += __shfl_xor(a, 32); b += __shfl_xor(b, 32);
  c += __shfl_xor(c, 32); d += __shfl_xor(d, 32);
}
__device__ __forceinline__ float wsum_step1(float a) {
  a = dpp_add<0xB1>(a); a = dpp_add<0x4E>(a);
  a = dpp_add<0x141>(a); a = dpp_add<0x140>(a);
  a += __shfl_xor(a, 16); a += __shfl_xor(a, 32);
  return a;
}

#define D2(rd, k) fmaf(rd.x, cx[k], fmaf(rd.y, cy[k],                      \
                   fmaf(rd.z, cz[k], rd.w + rc2[k])))

// init + point prep (SoA float4 with precomputed norms).
__global__ __launch_bounds__(256) void k_init(const float* __restrict__ gen,
                                              const float* __restrict__ gt) {
  const int i = blockIdx.x*256 + threadIdx.x;   // 64 x 256 = 16384 = B*N
  g_cbuf[0][i] = 0.f;
  g_cbuf[1][i] = 0.f;
  g_rbuf[0][i] = 1.f;
  const float tx = gt[i*3], ty = gt[i*3+1], tz = gt[i*3+2];
  g_gt4[i] = make_float4(tx, ty, tz, tx*tx + ty*ty + tz*tz);
  const float px = gen[i*3], py = gen[i*3+1], pz = gen[i*3+2];
  g_gen4[i] = make_float4(-2.f*px, -2.f*py, -2.f*pz, px*px + py*py + pz*pz);
  if (i == 0) g_cost = 0.f;
}

// A-part of level 0 (remainl = remainr = 1): computes s(0), colsum(0).
// 8 rows per round, one barrier per round (4 rounds).
__global__ __launch_bounds__(TPB) void k_a0(float c1) {
  const int blk = blockIdx.x, b = blk >> 6, chunk = blk & (CHUNKS-1);
  const int t = threadIdx.x, wave = t >> 6, lane = t & 63;
  const int rowbase = b*NPTS + chunk*RPB;
  __shared__ float4 rowdat[RPB];
  __shared__ float4 red[2][4][2];      // [buf][wave][half]: s1 of rows 0-3,4-7
  float cx[KC], cy[KC], cz[KC], rc2[KC];
  #pragma unroll
  for (int k = 0; k < KC; ++k) {
    const float4 q = g_gt4[b*MPTS + t + TPB*k];
    cx[k] = q.x; cy[k] = q.y; cz[k] = q.z; rc2[k] = q.w;
  }
  if (t < RPB) {
    rowdat[t] = g_gen4[rowbase + t];
    g_remainl[rowbase + t] = 1.0f;
  }
  __syncthreads();
  float colacc[KC];
  #pragma unroll
  for (int k = 0; k < KC; ++k) colacc[k] = 0.f;
  #pragma unroll 1
  for (int rr = 0; rr < NRND; ++rr) {
    const int r0 = RPR*rr;
    float w[RPR][KC], s1[RPR];
    #pragma unroll
    for (int j = 0; j < RPR; ++j) s1[j] = 0.f;
    #pragma unroll
    for (int j = 0; j < RPR; ++j) {
      const float4 rd = rowdat[r0 + j];
      #pragma unroll
      for (int k = 0; k < KC; ++k) {
        const float e = EXP2(c1*D2(rd, k));
        w[j][k] = e; s1[j] += e;
      }
    }
    wsum_step4(s1[0], s1[1], s1[2], s1[3]);
    wsum_step4(s1[4], s1[5], s1[6], s1[7]);
    if (lane == 0) {
      red[rr&1][wave][0] = make_float4(s1[0], s1[1], s1[2], s1[3]);
      red[rr&1][wave][1] = make_float4(s1[4], s1[5], s1[6], s1[7]);
    }
    __syncthreads();
    float scn[RPR];
    #pragma unroll
    for (int h = 0; h < 2; ++h) {
      const float4 v0 = red[rr&1][0][h], v1 = red[rr&1][1][h];
      const float4 v2 = red[rr&1][2][h], v3 = red[rr&1][3][h];
      scn[4*h+0] = RCP(v0.x+v1.x+v2.x+v3.x + 1e-9f);   // remainl = 1
      scn[4*h+1] = RCP(v0.y+v1.y+v2.y+v3.y + 1e-9f);
      scn[4*h+2] = RCP(v0.z+v1.z+v2.z+v3.z + 1e-9f);
      scn[4*h+3] = RCP(v0.w+v1.w+v2.w+v3.w + 1e-9f);
    }
    if (t == 0) {
      #pragma unroll
      for (int j = 0; j < RPR; ++j) g_s[rowbase + r0 + j] = scn[j];
    }
    #pragma unroll
    for (int k = 0; k < KC; ++k) {
      float acc = colacc[k];
      #pragma unroll
      for (int j = 0; j < RPR; ++j) acc = fmaf(w[j][k], scn[j], acc);
      colacc[k] = acc;
    }
  }
  #pragma unroll
  for (int k = 0; k < KC; ++k)
    atomicAdd(&g_cbuf[0][b*MPTS + t + TPB*k], colacc[k]);   // remainr == 1
}

// Fused [k_cols(l)] + C(level l) + A(level l+1); 8 rows/round, 4 rounds.
// eq = exp2(cq*d2) is next level's exp; e1 = (eq^2)^2 (c1 = 4*cq exactly).
// LAST (l==8): next level coeff is 0 -> eq = 1.
template<bool LAST>
__global__ __launch_bounds__(TPB) void k_ca(float c1, float cq, int l) {
  const int blk = blockIdx.x, b = blk >> 6, chunk = blk & (CHUNKS-1);
  const int t = threadIdx.x, wave = t >> 6, lane = t & 63;
  const int rowbase = b*NPTS + chunk*RPB;
  const float* __restrict__ cs_in = g_cbuf[l % 3];
  float* __restrict__ cs_out  = g_cbuf[(l+1) % 3];
  float* __restrict__ cs_zero = g_cbuf[(l+2) % 3];
  const float* __restrict__ rr_in = g_rbuf[l & 1];
  float* __restrict__ rr_out = g_rbuf[(l+1) & 1];
  __shared__ float4 rowdat[RPB];
  __shared__ float  sc_s[RPB], rl_s[RPB];
  __shared__ float4 red[2][4][4];      // [buf][wave][q]: s1 lo/hi, rs lo/hi
  __shared__ float  cred[4];
  // column stage + folded k_cols (global writes gated to chunk==0)
  float cx[KC], cy[KC], cz[KC], rc2[KC], pp[KC], rrn[KC];
  #pragma unroll
  for (int k = 0; k < KC; ++k) {
    const int m = b*MPTS + t + TPB*k;
    const float4 q = g_gt4[m];
    cx[k] = q.x; cy[k] = q.y; cz[k] = q.z; rc2[k] = q.w;
    const float cs = cs_in[m], rrv = rr_in[m];
    const float ratio = fminf(rrv / (cs + 1e-9f), 1.0f);
    pp[k]  = rrv*ratio;
    rrn[k] = fmaxf(rrv - cs*ratio, 0.0f);
    if (chunk == 0) { rr_out[m] = rrn[k]; cs_zero[m] = 0.0f; }
  }
  if (t < RPB) {
    rowdat[t] = g_gen4[rowbase + t];
    sc_s[t] = g_s[rowbase + t];
    rl_s[t] = g_remainl[rowbase + t];
  }
  __syncthreads();
  float colacc[KC];
  #pragma unroll
  for (int k = 0; k < KC; ++k) colacc[k] = 0.f;
  float costacc = 0.f;
  #pragma unroll 1
  for (int rr = 0; rr < NRND; ++rr) {
    const int r0 = RPR*rr;
    float w[RPR][KC], s1[RPR], rs[RPR];
    #pragma unroll
    for (int j = 0; j < RPR; ++j) { s1[j] = 0.f; rs[j] = 0.f; }
    #pragma unroll
    for (int j = 0; j < RPR; ++j) {
      const float4 rd = rowdat[r0 + j];
      float s2 = 0.f;
      #pragma unroll
      for (int k = 0; k < KC; ++k) {
        const float d2 = D2(rd, k);
        float e1, wq;
        if (LAST) { e1 = EXP2(c1*d2); wq = rrn[k]; }
        else { const float eq = EXP2(cq*d2); const float q2 = eq*eq;
               e1 = q2*q2; wq = eq*rrn[k]; }
        w[j][k] = wq; rs[j] += wq;
        const float u = e1*pp[k];
        s1[j] += u;
        s2 = fmaf(u, FSQRT(fmaxf(d2, 1e-20f)), s2);
      }
      costacc = fmaf(sc_s[r0 + j], s2, costacc);
    }
    wsum_step4(s1[0], s1[1], s1[2], s1[3]);
    wsum_step4(s1[4], s1[5], s1[6], s1[7]);
    wsum_step4(rs[0], rs[1], rs[2], rs[3]);
    wsum_step4(rs[4], rs[5], rs[6], rs[7]);
    if (lane == 0) {
      red[rr&1][wave][0] = make_float4(s1[0], s1[1], s1[2], s1[3]);
      red[rr&1][wave][1] = make_float4(s1[4], s1[5], s1[6], s1[7]);
      red[rr&1][wave][2] = make_float4(rs[0], rs[1], rs[2], rs[3]);
      red[rr&1][wave][3] = make_float4(rs[4], rs[5], rs[6], rs[7]);
    }
    __syncthreads();
    float scn[RPR];
    #pragma unroll
    for (int h = 0; h < 2; ++h) {
      const float4 a0 = red[rr&1][0][h],   a1 = red[rr&1][1][h];
      const float4 a2 = red[rr&1][2][h],   a3 = red[rr&1][3][h];
      const float4 b0 = red[rr&1][0][h+2], b1 = red[rr&1][1][h+2];
      const float4 b2 = red[rr&1][2][h+2], b3 = red[rr&1][3][h+2];
      const float s1t[4] = {a0.x+a1.x+a2.x+a3.x, a0.y+a1.y+a2.y+a3.y,
                            a0.z+a1.z+a2.z+a3.z, a0.w+a1.w+a2.w+a3.w};
      const float rst[4] = {b0.x+b1.x+b2.x+b3.x, b0.y+b1.y+b2.y+b3.y,
                            b0.z+b1.z+b2.z+b3.z, b0.w+b1.w+b2.w+b3.w};
      #pragma unroll
      for (int jj = 0; jj < 4; ++jj) {
        const int row = r0 + 4*h + jj;
        const float rln = fmaxf(rl_s[row] - sc_s[row]*s1t[jj], 0.0f);
        const float sv = rln * RCP(rst[jj] + 1e-9f);
        scn[4*h+jj] = sv;
        if (t == 0) {
          g_remainl[rowbase + row] = rln;
          g_s[rowbase + row] = sv;
        }
      }
    }
    #pragma unroll
    for (int k = 0; k < KC; ++k) {
      float acc = colacc[k];
      #pragma unroll
      for (int j = 0; j < RPR; ++j) acc = fmaf(w[j][k], scn[j], acc);
      colacc[k] = acc;
    }
  }
  #pragma unroll
  for (int k = 0; k < KC; ++k)
    atomicAdd(&cs_out[b*MPTS + t + TPB*k], colacc[k]);
  costacc = wsum_step1(costacc);
  if (lane == 0) cred[wave] = costacc;
  __syncthreads();
  if (t == 0)
    atomicAdd(&g_cost, cred[0] + cred[1] + cred[2] + cred[3]);
}

// C-part of level 9 (coeff 0 -> weight = p): cost only, barrier-free loop.
// Reads colsum from cbuf[9%3=0], remainr from rbuf[9&1=1].
__global__ __launch_bounds__(TPB) void k_c_last() {
  const int blk = blockIdx.x, b = blk >> 6, chunk = blk & (CHUNKS-1);
  const int t = threadIdx.x, wave = t >> 6, lane = t & 63;
  const int rowbase = b*NPTS + chunk*RPB;
  const float* __restrict__ cs_in = g_cbuf[0];
  const float* __restrict__ rr_in = g_rbuf[1];
  __shared__ float4 rowdat[RPB];
  __shared__ float  sc_s[RPB];
  __shared__ float  cred[4];
  float cx[KC], cy[KC], cz[KC], rc2[KC], pp[KC];
  #pragma unroll
  for (int k = 0; k < KC; ++k) {
    const int m = b*MPTS + t + TPB*k;
    const float4 q = g_gt4[m];
    cx[k] = q.x; cy[k] = q.y; cz[k] = q.z; rc2[k] = q.w;
    const float cs = cs_in[m], rrv = rr_in[m];
    const float ratio = fminf(rrv / (cs + 1e-9f), 1.0f);
    pp[k] = rrv*ratio;
  }
  if (t < RPB) {
    rowdat[t] = g_gen4[rowbase + t];
    sc_s[t] = g_s[rowbase + t];
  }
  __syncthreads();
  float costacc = 0.f;
  #pragma unroll 1
  for (int r = 0; r < RPB; ++r) {
    const float4 rd = rowdat[r];
    float s2 = 0.f;
    #pragma unroll
    for (int k = 0; k < KC; ++k)
      s2 = fmaf(pp[k], FSQRT(fmaxf(D2(rd, k), 1e-20f)), s2);
    costacc = fmaf(sc_s[r], s2, costacc);
  }
  costacc = wsum_step1(costacc);
  if (lane == 0) cred[wave] = costacc;
  __syncthreads();
  if (t == 0)
    atomicAdd(&g_cost, cred[0] + cred[1] + cred[2] + cred[3]);
}

__global__ void k_final(float* __restrict__ out) {
  out[0] = g_cost * (1.0f / (float)(BATCH*NPTS));
}

extern "C" void kernel_launch(void* const* d_in, const int* in_sizes, int n_in,
                              void* d_out, int out_size, void* d_ws, size_t ws_size,
                              hipStream_t stream) {
  const float* gen = (const float*)d_in[0];   // pc_gen [8,2048,3] f32
  const float* gt  = (const float*)d_in[1];   // pc_gt  [8,2048,3] f32
  float* out = (float*)d_out;

  const double L[10] = {-16384.0, -4096.0, -1024.0, -256.0, -64.0,
                        -16.0, -4.0, -1.0, -0.25, 0.0};
  float c[10];
  for (int i = 0; i < 10; ++i) c[i] = (float)(L[i] * 1.4426950408889634);

  k_init<<<64, 256, 0, stream>>>(gen, gt);
  k_a0<<<NBLK, TPB, 0, stream>>>(c[0]);
  for (int l = 0; l < 8; ++l)
    k_ca<false><<<NBLK, TPB, 0, stream>>>(c[l], c[l+1], l);
  k_ca<true><<<NBLK, TPB, 0, stream>>>(c[8], 0.f, 8);
  k_c_last<<<NBLK, TPB, 0, stream>>>();
  k_final<<<1, 1, 0, stream>>>(out);
}

// Round 21
// 300.302 us; speedup vs baseline: 1.3326x; 1.3326x over previous
//
#include <hip/hip_runtime.h>
#include <math.h>

#define BATCH 8
#define NPTS 2048
#define MPTS 2048
#define TPB 256                       // 4 waves
#define RPB 32                        // rows per block
#define KC 8                          // columns per thread: 2048/256
#define RPR 4                         // rows per round (measured optimum)
#define NRND (RPB/RPR)                // 8 rounds
#define CHUNKS (NPTS/RPB)             // 64
#define NBLK (BATCH*CHUNKS)           // 512

// Persistent state (re-initialized every kernel_launch -> deterministic).
// colsum rotation: level l reads g_cbuf[l%3], accumulates into g_cbuf[(l+1)%3],
// zeroes g_cbuf[(l+2)%3]. remainr ping-pongs g_rbuf[l&1] -> g_rbuf[(l+1)&1].
// rr/zero global writes gated to chunk==0 (identical values across blocks).
__device__ float  g_remainl[BATCH*NPTS];
__device__ float  g_s[BATCH*NPTS];
__device__ float  g_rbuf[2][BATCH*MPTS];
__device__ float  g_cbuf[3][BATCH*MPTS];
__device__ float4 g_gt4[BATCH*MPTS];   // (x, y, z, |c|^2)
__device__ float4 g_gen4[BATCH*NPTS];  // (-2x, -2y, -2z, |g|^2)
__device__ float  g_cost;

#if __has_builtin(__builtin_amdgcn_exp2f)
#define EXP2(x) __builtin_amdgcn_exp2f(x)
#else
#define EXP2(x) exp2f(x)
#endif
#if __has_builtin(__builtin_amdgcn_sqrtf)
#define FSQRT(x) __builtin_amdgcn_sqrtf(x)
#else
#define FSQRT(x) sqrtf(x)
#endif
#if __has_builtin(__builtin_amdgcn_rcpf)
#define RCP(x) __builtin_amdgcn_rcpf(x)
#else
#define RCP(x) (1.0f/(x))
#endif

template<int CTRL>
__device__ __forceinline__ float dpp_add(float x) {
  const int y = __builtin_amdgcn_update_dpp(0, __float_as_int(x),
                                            CTRL, 0xF, 0xF, true);
  return x + __int_as_float(y);
}
__device__ __forceinline__ void wsum_step4(float& a, float& b, float& c, float& d) {
  a = dpp_add<0xB1>(a);  b = dpp_add<0xB1>(b);
  c = dpp_add<0xB1>(c);  d = dpp_add<0xB1>(d);
  a = dpp_add<0x4E>(a);  b = dpp_add<0x4E>(b);
  c = dpp_add<0x4E>(c);  d = dpp_add<0x4E>(d);
  a = dpp_add<0x141>(a); b = dpp_add<0x141>(b);
  c = dpp_add<0x141>(c); d = dpp_add<0x141>(d);
  a = dpp_add<0x140>(a); b = dpp_add<0x140>(b);
  c = dpp_add<0x140>(c); d = dpp_add<0x140>(d);
  a += __shfl_xor(a, 16); b += __shfl_xor(b, 16);
  c += __shfl_xor(c, 16); d += __shfl_xor(d, 16);
  a += __shfl_xor(a, 32); b += __shfl_xor(b, 32);
  c += __shfl_xor(c, 32); d += __shfl_xor(d, 32);
}
__device__ __forceinline__ float wsum_step1(float a) {
  a = dpp_add<0xB1>(a); a = dpp_add<0x4E>(a);
  a = dpp_add<0x141>(a); a = dpp_add<0x140>(a);
  a += __shfl_xor(a, 16); a += __shfl_xor(a, 32);
  return a;
}

#define D2(rd, k) fmaf(rd.x, cx[k], fmaf(rd.y, cy[k],                      \
                   fmaf(rd.z, cz[k], rd.w + rc2[k])))

// init + point prep (SoA float4 with precomputed norms).
__global__ __launch_bounds__(256) void k_init(const float* __restrict__ gen,
                                              const float* __restrict__ gt) {
  const int i = blockIdx.x*256 + threadIdx.x;   // 64 x 256 = 16384 = B*N
  g_cbuf[0][i] = 0.f;
  g_cbuf[1][i] = 0.f;
  g_rbuf[0][i] = 1.f;
  const float tx = gt[i*3], ty = gt[i*3+1], tz = gt[i*3+2];
  g_gt4[i] = make_float4(tx, ty, tz, tx*tx + ty*ty + tz*tz);
  const float px = gen[i*3], py = gen[i*3+1], pz = gen[i*3+2];
  g_gen4[i] = make_float4(-2.f*px, -2.f*py, -2.f*pz, px*px + py*py + pz*pz);
  if (i == 0) g_cost = 0.f;
}

// A-part of level 0 (remainl = remainr = 1): computes s(0), colsum(0).
// 4 rows per round, one barrier per round.
__global__ __launch_bounds__(TPB) void k_a0(float c1) {
  const int blk = blockIdx.x, b = blk >> 6, chunk = blk & (CHUNKS-1);
  const int t = threadIdx.x, wave = t >> 6, lane = t & 63;
  const int rowbase = b*NPTS + chunk*RPB;
  __shared__ float4 rowdat[RPB];
  __shared__ float4 red[2][4];         // [buf][wave]: s1 of 4 rows
  float cx[KC], cy[KC], cz[KC], rc2[KC];
  #pragma unroll
  for (int k = 0; k < KC; ++k) {
    const float4 q = g_gt4[b*MPTS + t + TPB*k];
    cx[k] = q.x; cy[k] = q.y; cz[k] = q.z; rc2[k] = q.w;
  }
  if (t < RPB) {
    rowdat[t] = g_gen4[rowbase + t];
    g_remainl[rowbase + t] = 1.0f;
  }
  __syncthreads();
  float colacc[KC];
  #pragma unroll
  for (int k = 0; k < KC; ++k) colacc[k] = 0.f;
  #pragma unroll 1
  for (int rr = 0; rr < NRND; ++rr) {
    const float4 rd0 = rowdat[4*rr+0], rd1 = rowdat[4*rr+1];
    const float4 rd2 = rowdat[4*rr+2], rd3 = rowdat[4*rr+3];
    float wA[KC], wB[KC], wC[KC], wD[KC];
    float s1a = 0.f, s1b = 0.f, s1c = 0.f, s1d = 0.f;
    #pragma unroll
    for (int k = 0; k < KC; ++k) {
      const float ea = EXP2(c1*D2(rd0, k));
      const float eb = EXP2(c1*D2(rd1, k));
      const float ec = EXP2(c1*D2(rd2, k));
      const float ed = EXP2(c1*D2(rd3, k));
      wA[k] = ea; s1a += ea;
      wB[k] = eb; s1b += eb;
      wC[k] = ec; s1c += ec;
      wD[k] = ed; s1d += ed;
    }
    wsum_step4(s1a, s1b, s1c, s1d);
    if (lane == 0) red[rr&1][wave] = make_float4(s1a, s1b, s1c, s1d);
    __syncthreads();
    const float4 v0 = red[rr&1][0], v1 = red[rr&1][1];
    const float4 v2 = red[rr&1][2], v3 = red[rr&1][3];
    const float scn0 = RCP(v0.x+v1.x+v2.x+v3.x + 1e-9f);   // remainl = 1
    const float scn1 = RCP(v0.y+v1.y+v2.y+v3.y + 1e-9f);
    const float scn2 = RCP(v0.z+v1.z+v2.z+v3.z + 1e-9f);
    const float scn3 = RCP(v0.w+v1.w+v2.w+v3.w + 1e-9f);
    if (t == 0) {
      g_s[rowbase + 4*rr + 0] = scn0;
      g_s[rowbase + 4*rr + 1] = scn1;
      g_s[rowbase + 4*rr + 2] = scn2;
      g_s[rowbase + 4*rr + 3] = scn3;
    }
    #pragma unroll
    for (int k = 0; k < KC; ++k)
      colacc[k] = fmaf(wA[k], scn0, fmaf(wB[k], scn1,
                  fmaf(wC[k], scn2, fmaf(wD[k], scn3, colacc[k]))));
  }
  #pragma unroll
  for (int k = 0; k < KC; ++k)
    atomicAdd(&g_cbuf[0][b*MPTS + t + TPB*k], colacc[k]);   // remainr == 1
}

// Fused [k_cols(l)] + C(level l) + A(level l+1); 4 rows/round, 8 rounds.
// eq = exp2(cq*d2) is next level's exp; e1 = (eq^2)^2 (c1 = 4*cq exactly).
// LAST (l==8): next level coeff is 0 -> eq = 1.
template<bool LAST>
__global__ __launch_bounds__(TPB) void k_ca(float c1, float cq, int l) {
  const int blk = blockIdx.x, b = blk >> 6, chunk = blk & (CHUNKS-1);
  const int t = threadIdx.x, wave = t >> 6, lane = t & 63;
  const int rowbase = b*NPTS + chunk*RPB;
  const float* __restrict__ cs_in = g_cbuf[l % 3];
  float* __restrict__ cs_out  = g_cbuf[(l+1) % 3];
  float* __restrict__ cs_zero = g_cbuf[(l+2) % 3];
  const float* __restrict__ rr_in = g_rbuf[l & 1];
  float* __restrict__ rr_out = g_rbuf[(l+1) & 1];
  __shared__ float4 rowdat[RPB];
  __shared__ float  sc_s[RPB], rl_s[RPB];
  __shared__ float4 red[2][4][2];      // [buf][wave][0]=s1x4 [1]=rsx4
  __shared__ float  cred[4];
  // column stage + folded k_cols (global writes gated to chunk==0)
  float cx[KC], cy[KC], cz[KC], rc2[KC], pp[KC], rrn[KC];
  #pragma unroll
  for (int k = 0; k < KC; ++k) {
    const int m = b*MPTS + t + TPB*k;
    const float4 q = g_gt4[m];
    cx[k] = q.x; cy[k] = q.y; cz[k] = q.z; rc2[k] = q.w;
    const float cs = cs_in[m], rrv = rr_in[m];
    const float ratio = fminf(rrv / (cs + 1e-9f), 1.0f);
    pp[k]  = rrv*ratio;
    rrn[k] = fmaxf(rrv - cs*ratio, 0.0f);
    if (chunk == 0) { rr_out[m] = rrn[k]; cs_zero[m] = 0.0f; }
  }
  if (t < RPB) {
    rowdat[t] = g_gen4[rowbase + t];
    sc_s[t] = g_s[rowbase + t];
    rl_s[t] = g_remainl[rowbase + t];
  }
  __syncthreads();
  float colacc[KC];
  #pragma unroll
  for (int k = 0; k < KC; ++k) colacc[k] = 0.f;
  float costacc = 0.f;
  #pragma unroll 1
  for (int rr = 0; rr < NRND; ++rr) {
    const int r0 = 4*rr;
    const float4 rd0 = rowdat[r0+0], rd1 = rowdat[r0+1];
    const float4 rd2 = rowdat[r0+2], rd3 = rowdat[r0+3];
    float wA[KC], wB[KC], wC[KC], wD[KC];
    float s1a = 0.f, rsa = 0.f, s2a = 0.f;
    float s1b = 0.f, rsb = 0.f, s2b = 0.f;
    float s1c = 0.f, rsc = 0.f, s2c = 0.f;
    float s1d = 0.f, rsd = 0.f, s2d = 0.f;
    #pragma unroll
    for (int k = 0; k < KC; ++k) {
      const float d2a = D2(rd0, k), d2b = D2(rd1, k);
      const float d2c = D2(rd2, k), d2d = D2(rd3, k);
      float e1a, wqa, e1b, wqb, e1c, wqc, e1d, wqd;
      if (LAST) {
        e1a = EXP2(c1*d2a); wqa = rrn[k];
        e1b = EXP2(c1*d2b); wqb = rrn[k];
        e1c = EXP2(c1*d2c); wqc = rrn[k];
        e1d = EXP2(c1*d2d); wqd = rrn[k];
      } else {
        const float eqa = EXP2(cq*d2a); const float q2a = eqa*eqa;
        e1a = q2a*q2a; wqa = eqa*rrn[k];
        const float eqb = EXP2(cq*d2b); const float q2b = eqb*eqb;
        e1b = q2b*q2b; wqb = eqb*rrn[k];
        const float eqc = EXP2(cq*d2c); const float q2c = eqc*eqc;
        e1c = q2c*q2c; wqc = eqc*rrn[k];
        const float eqd = EXP2(cq*d2d); const float q2d = eqd*eqd;
        e1d = q2d*q2d; wqd = eqd*rrn[k];
      }
      wA[k] = wqa; rsa += wqa;
      wB[k] = wqb; rsb += wqb;
      wC[k] = wqc; rsc += wqc;
      wD[k] = wqd; rsd += wqd;
      const float ua = e1a*pp[k], ub = e1b*pp[k];
      const float uc = e1c*pp[k], ud = e1d*pp[k];
      s1a += ua; s1b += ub; s1c += uc; s1d += ud;
      s2a = fmaf(ua, FSQRT(fmaxf(d2a, 1e-20f)), s2a);
      s2b = fmaf(ub, FSQRT(fmaxf(d2b, 1e-20f)), s2b);
      s2c = fmaf(uc, FSQRT(fmaxf(d2c, 1e-20f)), s2c);
      s2d = fmaf(ud, FSQRT(fmaxf(d2d, 1e-20f)), s2d);
    }
    costacc = fmaf(sc_s[r0+0], s2a, costacc);
    costacc = fmaf(sc_s[r0+1], s2b, costacc);
    costacc = fmaf(sc_s[r0+2], s2c, costacc);
    costacc = fmaf(sc_s[r0+3], s2d, costacc);
    wsum_step4(s1a, s1b, s1c, s1d);
    wsum_step4(rsa, rsb, rsc, rsd);
    if (lane == 0) {
      red[rr&1][wave][0] = make_float4(s1a, s1b, s1c, s1d);
      red[rr&1][wave][1] = make_float4(rsa, rsb, rsc, rsd);
    }
    __syncthreads();
    const float4 a0 = red[rr&1][0][0], a1 = red[rr&1][1][0];
    const float4 a2 = red[rr&1][2][0], a3 = red[rr&1][3][0];
    const float4 b0 = red[rr&1][0][1], b1 = red[rr&1][1][1];
    const float4 b2 = red[rr&1][2][1], b3 = red[rr&1][3][1];
    const float s1t0 = a0.x+a1.x+a2.x+a3.x, rst0 = b0.x+b1.x+b2.x+b3.x;
    const float s1t1 = a0.y+a1.y+a2.y+a3.y, rst1 = b0.y+b1.y+b2.y+b3.y;
    const float s1t2 = a0.z+a1.z+a2.z+a3.z, rst2 = b0.z+b1.z+b2.z+b3.z;
    const float s1t3 = a0.w+a1.w+a2.w+a3.w, rst3 = b0.w+b1.w+b2.w+b3.w;
    const float rl0 = fmaxf(rl_s[r0+0] - sc_s[r0+0]*s1t0, 0.0f);
    const float rl1 = fmaxf(rl_s[r0+1] - sc_s[r0+1]*s1t1, 0.0f);
    const float rl2 = fmaxf(rl_s[r0+2] - sc_s[r0+2]*s1t2, 0.0f);
    const float rl3 = fmaxf(rl_s[r0+3] - sc_s[r0+3]*s1t3, 0.0f);
    const float scn0 = rl0 * RCP(rst0 + 1e-9f);
    const float scn1 = rl1 * RCP(rst1 + 1e-9f);
    const float scn2 = rl2 * RCP(rst2 + 1e-9f);
    const float scn3 = rl3 * RCP(rst3 + 1e-9f);
    if (t == 0) {
      g_remainl[rowbase + r0+0] = rl0; g_s[rowbase + r0+0] = scn0;
      g_remainl[rowbase + r0+1] = rl1; g_s[rowbase + r0+1] = scn1;
      g_remainl[rowbase + r0+2] = rl2; g_s[rowbase + r0+2] = scn2;
      g_remainl[rowbase + r0+3] = rl3; g_s[rowbase + r0+3] = scn3;
    }
    #pragma unroll
    for (int k = 0; k < KC; ++k)
      colacc[k] = fmaf(wA[k], scn0, fmaf(wB[k], scn1,
                  fmaf(wC[k], scn2, fmaf(wD[k], scn3, colacc[k]))));
  }
  #pragma unroll
  for (int k = 0; k < KC; ++k)
    atomicAdd(&cs_out[b*MPTS + t + TPB*k], colacc[k]);
  costacc = wsum_step1(costacc);
  if (lane == 0) cred[wave] = costacc;
  __syncthreads();
  if (t == 0)
    atomicAdd(&g_cost, cred[0] + cred[1] + cred[2] + cred[3]);
}

// C-part of level 9 (coeff 0 -> weight = p): cost only, barrier-free loop.
// Reads colsum from cbuf[9%3=0], remainr from rbuf[9&1=1].
__global__ __launch_bounds__(TPB) void k_c_last() {
  const int blk = blockIdx.x, b = blk >> 6, chunk = blk & (CHUNKS-1);
  const int t = threadIdx.x, wave = t >> 6, lane = t & 63;
  const int rowbase = b*NPTS + chunk*RPB;
  const float* __restrict__ cs_in = g_cbuf[0];
  const float* __restrict__ rr_in = g_rbuf[1];
  __shared__ float4 rowdat[RPB];
  __shared__ float  sc_s[RPB];
  __shared__ float  cred[4];
  float cx[KC], cy[KC], cz[KC], rc2[KC], pp[KC];
  #pragma unroll
  for (int k = 0; k < KC; ++k) {
    const int m = b*MPTS + t + TPB*k;
    const float4 q = g_gt4[m];
    cx[k] = q.x; cy[k] = q.y; cz[k] = q.z; rc2[k] = q.w;
    const float cs = cs_in[m], rrv = rr_in[m];
    const float ratio = fminf(rrv / (cs + 1e-9f), 1.0f);
    pp[k] = rrv*ratio;
  }
  if (t < RPB) {
    rowdat[t] = g_gen4[rowbase + t];
    sc_s[t] = g_s[rowbase + t];
  }
  __syncthreads();
  float costacc = 0.f;
  #pragma unroll 1
  for (int r = 0; r < RPB; ++r) {
    const float4 rd = rowdat[r];
    float s2 = 0.f;
    #pragma unroll
    for (int k = 0; k < KC; ++k)
      s2 = fmaf(pp[k], FSQRT(fmaxf(D2(rd, k), 1e-20f)), s2);
    costacc = fmaf(sc_s[r], s2, costacc);
  }
  costacc = wsum_step1(costacc);
  if (lane == 0) cred[wave] = costacc;
  __syncthreads();
  if (t == 0)
    atomicAdd(&g_cost, cred[0] + cred[1] + cred[2] + cred[3]);
}

__global__ void k_final(float* __restrict__ out) {
  out[0] = g_cost * (1.0f / (float)(BATCH*NPTS));
}

extern "C" void kernel_launch(void* const* d_in, const int* in_sizes, int n_in,
                              void* d_out, int out_size, void* d_ws, size_t ws_size,
                              hipStream_t stream) {
  const float* gen = (const float*)d_in[0];   // pc_gen [8,2048,3] f32
  const float* gt  = (const float*)d_in[1];   // pc_gt  [8,2048,3] f32
  float* out = (float*)d_out;

  const double L[10] = {-16384.0, -4096.0, -1024.0, -256.0, -64.0,
                        -16.0, -4.0, -1.0, -0.25, 0.0};
  float c[10];
  for (int i = 0; i < 10; ++i) c[i] = (float)(L[i] * 1.4426950408889634);

  k_init<<<64, 256, 0, stream>>>(gen, gt);
  k_a0<<<NBLK, TPB, 0, stream>>>(c[0]);
  for (int l = 0; l < 8; ++l)
    k_ca<false><<<NBLK, TPB, 0, stream>>>(c[l], c[l+1], l);
  k_ca<true><<<NBLK, TPB, 0, stream>>>(c[8], 0.f, 8);
  k_c_last<<<NBLK, TPB, 0, stream>>>();
  k_final<<<1, 1, 0, stream>>>(out);
}